// Round 2
// baseline (600.806 us; speedup 1.0000x reference)
//
#include <hip/hip_runtime.h>
#include <math.h>

#define NB 256      // batch / time steps
#define NV 100      // visits
#define NC 40       // codes per visit
#define NE 128      // embed dim (LSTM "batch")
#define NH 100      // hidden (== feat)
#define NG 400      // 4*NH

// ws layout (float elements)
#define OFF_SUM   0
#define N_SUM     (NB*NV*NE)                 // 3,276,800  (x2 viewed [32768][100])
#define OFF_PRE   (OFF_SUM + N_SUM)
#define N_PRE     (NB*NE*NG)                 // 13,107,200
#define OFF_TRUH  (OFF_PRE + N_PRE)
#define N_TRUH    (NB*NE)                    // 32,768
#define OFF_LAST  (OFF_TRUH + N_TRUH)        // ints, 256

// ---------------------------------------------------------------- kernel 1
// masked embedding sum  +  last-visit segment max
__global__ __launch_bounds__(128) void k_embed(
    const int* __restrict__ diag, const float* __restrict__ mask,
    const float* __restrict__ table, float* __restrict__ sumembed,
    int* __restrict__ last) {
  int bv = blockIdx.x;              // 0..25599
  int b  = bv / NV;
  int v  = bv - b * NV;
  int base = bv * NC;
  int e = threadIdx.x;              // 0..127
  float acc = 0.f;
  float msum = 0.f;
  for (int c = 0; c < NC; ++c) {
    float m = mask[base + c];       // wave-uniform -> scalar load
    msum += m;
    if (m != 0.f) {                 // uniform branch, skips dead gathers
      int idx = diag[base + c];     // wave-uniform
      acc = fmaf(m, table[idx * NE + e], acc);
    }
  }
  sumembed[bv * NE + e] = acc;
  if (e == 0 && msum > 0.f) atomicMax(&last[b], v);
}

// ---------------------------------------------------------------- kernel 2
// pre[t*128+e][q] = x2[m][:] . W_ih[jmap(q)][:] + bias[jmap(q)]
// M=32768, K=100, N=400.  64x64 tiles, 4x4 register tiles.
// OUTPUT COLUMNS ARE PERMUTED: q = u*4+g  <->  gate row j = g*100+u, so that
// k_lstm thread tid reads pre[..+tid] coalesced with the gate-interleaved
// thread mapping. Per-value math identical (same k order, bias at store).
__global__ __launch_bounds__(256) void k_pregemm(
    const float* __restrict__ x2, const float* __restrict__ Wih,
    const float* __restrict__ bih, const float* __restrict__ bhh,
    float* __restrict__ pre) {
  __shared__ __align__(16) float As[100][68];   // [k][m], stride 68 => 16B aligned rows
  __shared__ __align__(16) float Bs[100][68];   // [k][n]
  __shared__ __align__(16) float bias_s[64];
  const int m0 = blockIdx.x * 64;
  const int n0 = blockIdx.y * 64;
  const int tid = threadIdx.x;

  for (int idx = tid; idx < 6400; idx += 256) {
    int m = idx / 100, k = idx - m * 100;
    As[k][m] = x2[(m0 + m) * 100 + k];          // coalesced along k
  }
  for (int idx = tid; idx < 6400; idx += 256) {
    int n = idx / 100, k = idx - n * 100;
    int q = n0 + n;                             // permuted output col
    int j = (q & 3) * 100 + (q >> 2);           // original gate row
    Bs[k][n] = (q < NG) ? Wih[j * 100 + k] : 0.f;
  }
  if (tid < 64) {
    int q = n0 + tid;
    int j = (q & 3) * 100 + (q >> 2);
    bias_s[tid] = (q < NG) ? (bih[j] + bhh[j]) : 0.f;
  }
  __syncthreads();

  const int tm = tid & 15, tn = tid >> 4;       // 16x16 thread grid, 4x4 each
  float acc[4][4] = {};
  #pragma unroll 4
  for (int k = 0; k < 100; ++k) {
    float4 a  = *(const float4*)&As[k][tm * 4];
    float4 bb = *(const float4*)&Bs[k][tn * 4];
    acc[0][0] = fmaf(a.x, bb.x, acc[0][0]); acc[0][1] = fmaf(a.x, bb.y, acc[0][1]);
    acc[0][2] = fmaf(a.x, bb.z, acc[0][2]); acc[0][3] = fmaf(a.x, bb.w, acc[0][3]);
    acc[1][0] = fmaf(a.y, bb.x, acc[1][0]); acc[1][1] = fmaf(a.y, bb.y, acc[1][1]);
    acc[1][2] = fmaf(a.y, bb.z, acc[1][2]); acc[1][3] = fmaf(a.y, bb.w, acc[1][3]);
    acc[2][0] = fmaf(a.z, bb.x, acc[2][0]); acc[2][1] = fmaf(a.z, bb.y, acc[2][1]);
    acc[2][2] = fmaf(a.z, bb.z, acc[2][2]); acc[2][3] = fmaf(a.z, bb.w, acc[2][3]);
    acc[3][0] = fmaf(a.w, bb.x, acc[3][0]); acc[3][1] = fmaf(a.w, bb.y, acc[3][1]);
    acc[3][2] = fmaf(a.w, bb.z, acc[3][2]); acc[3][3] = fmaf(a.w, bb.w, acc[3][3]);
  }

  if (n0 + tn * 4 < NG) {                       // whole float4 valid or none (400%4==0)
    float4 bb = *(const float4*)&bias_s[tn * 4];
    #pragma unroll
    for (int im = 0; im < 4; ++im) {
      int m = m0 + tm * 4 + im;
      float4 st;
      st.x = acc[im][0] + bb.x; st.y = acc[im][1] + bb.y;
      st.z = acc[im][2] + bb.z; st.w = acc[im][3] + bb.w;
      *(float4*)&pre[m * NG + n0 + tn * 4] = st;
    }
  }
}

// ---------------------------------------------------------------- kernel 3
// sequential LSTM, 128 blocks x 448 threads (7 waves), gate-interleaved
// thread map (tid -> u=tid>>2, g=tid&3, row j=g*100+u).
//
// R1 POST-MORTEM: the step floor was LDS RETURN BW, not barriers. 400
// threads x 100 h-floats = 175 ds_read_b128/CU/step x ~12cyc = 2100cyc
// == measured 2197cyc step. Fix: h[k] is wave-uniform, so broadcast it
// through the SCALAR path: each wave loads h into lanes once (2x
// ds_read_b32: lane l holds h[l], h[64+l]) and the GEMV uses
// v_readlane_b32 (compile-time lane index, VALU issue not LDS pipe) to
// feed v_fmac. LDS instr/CU/step: 175 -> ~21.
//
// readlane ignores EXEC -> the h0/h1 lane-loads are UNGUARDED (all 448
// threads execute them so every physical lane 0..63 of every wave holds
// valid h). Weight-row / pre indices are clamped for tid>=400 instead of
// guarded; only the cell update + stores are predicated.
__device__ __forceinline__ float fast_sigmoid(float x) {
  return 1.f / (1.f + __expf(-x));
}
__device__ __forceinline__ float fast_tanh(float x) {
  float ax = fabsf(x);
  float e  = __expf(-2.f * ax);
  float t  = (1.f - e) / (1.f + e);
  return x < 0.f ? -t : t;
}

__device__ __forceinline__ float rl(float v, int k) {   // k: compile-time const
  return __int_as_float(__builtin_amdgcn_readlane(__float_as_int(v), k));
}
// broadcast h[K] from the wave's lanes (h0: K<64, h1: K>=64), K literal
#define HK(K) ((K) < 64 ? rl(h0, (K)) : rl(h1, (K) - 64))
// one float4 weight group, same FMA order/accumulator as the old FMA4
#define GRP(KK, W, A)                                                     \
  A = fmaf(HK(4*(KK)+0), (W).x, A); A = fmaf(HK(4*(KK)+1), (W).y, A);     \
  A = fmaf(HK(4*(KK)+2), (W).z, A); A = fmaf(HK(4*(KK)+3), (W).w, A)

__global__ __launch_bounds__(448, 2) void k_lstm(
    const float* __restrict__ pre, const float* __restrict__ Whh,
    const int* __restrict__ last, float* __restrict__ truh) {
  __shared__ __align__(16) float hbuf[2][128];  // 128: lane-reads up to [127] stay in-bounds
  __shared__ int last_s[NB];
  const int e = blockIdx.x;         // 0..127
  const int tid = threadIdx.x;
  const int lane = tid & 63;
  const int u = tid >> 2, g = tid & 3;
  const int row  = g * 100 + u;     // gate-major W_hh row for this thread
  const int rowc = (row < NG) ? row : (NG - 1);   // clamp dead lanes (tid>=400)
  const int colc = (tid < NG) ? tid : (NG - 1);   // clamped pre column

  // 25 named float4 = 100 weight VGPRs. Whh row stride 400 B -> 16B aligned.
  const float4* wr = (const float4*)(Whh + rowc * 100);
  float4 w00 = wr[0],  w01 = wr[1],  w02 = wr[2],  w03 = wr[3],  w04 = wr[4],
         w05 = wr[5],  w06 = wr[6],  w07 = wr[7],  w08 = wr[8],  w09 = wr[9],
         w10 = wr[10], w11 = wr[11], w12 = wr[12], w13 = wr[13], w14 = wr[14],
         w15 = wr[15], w16 = wr[16], w17 = wr[17], w18 = wr[18], w19 = wr[19],
         w20 = wr[20], w21 = wr[21], w22 = wr[22], w23 = wr[23], w24 = wr[24];

  if (tid < 128) { hbuf[0][tid] = 0.f; hbuf[1][tid] = 0.f; }
  if (tid < NB) last_s[tid] = last[tid];  // stage once
  float c = 0.f;                    // cell state lives in g==0 lanes

  const float* pbase = pre + e * NG + colc;     // + t*51200 per step
  float p0 = pbase[0];
  float p1 = pbase[51200];
  float p2 = pbase[2 * 51200];
  __syncthreads();

  for (int t = 0; t < NB; ++t) {
    float p3 = (t + 3 < NB) ? pbase[(t + 3) * 51200] : 0.f;

    // UNGUARDED lane-loads: every lane of every wave must hold valid h
    // for readlane. h(t) lives in hbuf[t&1].
    float h0 = hbuf[t & 1][lane];
    float h1 = hbuf[t & 1][64 + lane];

    // GEMV: 100 readlane-broadcast FMAs, 4 rotating accumulator chains.
    // Same value order as R1's FMA4 ladder -> bit-identical.
    float a0 = p0, a1 = 0.f, a2 = 0.f, a3 = 0.f;
    GRP(0,  w00, a0); GRP(1,  w01, a1); GRP(2,  w02, a2); GRP(3,  w03, a3);
    GRP(4,  w04, a0); GRP(5,  w05, a1); GRP(6,  w06, a2); GRP(7,  w07, a3);
    GRP(8,  w08, a0); GRP(9,  w09, a1); GRP(10, w10, a2); GRP(11, w11, a3);
    GRP(12, w12, a0); GRP(13, w13, a1); GRP(14, w14, a2); GRP(15, w15, a3);
    GRP(16, w16, a0); GRP(17, w17, a1); GRP(18, w18, a2); GRP(19, w19, a3);
    GRP(20, w20, a0); GRP(21, w21, a1); GRP(22, w22, a2); GRP(23, w23, a3);
    GRP(24, w24, a0);
    float acc = (a0 + a1) + (a2 + a3);
    float act = (g == 2) ? fast_tanh(acc) : fast_sigmoid(acc);

    // gather unit u's gates within the 4-lane group (4-aligned, never
    // straddles a wave)
    float fg = __shfl_down(act, 1);   // f  (row 100+u)
    float gg = __shfl_down(act, 2);   // g  (row 200+u)
    float og = __shfl_down(act, 3);   // o  (row 300+u)
    if (g == 0 && u < NH) {           // act == i gate here
      c = fmaf(fg, c, act * gg);
      float hv = og * fast_tanh(c);
      hbuf[(t + 1) & 1][u] = hv;
      if (u == last_s[t]) truh[t * NE + e] = hv; // hs[b=t, e, last[t]]
    }
    __syncthreads();                  // h(t+1) visible; this step's reads drained
    p0 = p1; p1 = p2; p2 = p3;
  }
}

// ---------------------------------------------------------------- kernel 4
// out[b] = sigmoid( truh[b,:] . fc_w + fc_b )
__global__ __launch_bounds__(128) void k_fc(
    const float* __restrict__ truh, const float* __restrict__ fcw,
    const float* __restrict__ fcb, float* __restrict__ out) {
  int b = blockIdx.x, t = threadIdx.x;
  float v = truh[b * NE + t] * fcw[t];
  #pragma unroll
  for (int o = 32; o > 0; o >>= 1) v += __shfl_down(v, o);
  __shared__ float s[2];
  if ((t & 63) == 0) s[t >> 6] = v;
  __syncthreads();
  if (t == 0) {
    float sum = s[0] + s[1] + fcb[0];
    out[b] = 1.f / (1.f + __expf(-sum));
  }
}

// ---------------------------------------------------------------- launch
extern "C" void kernel_launch(void* const* d_in, const int* in_sizes, int n_in,
                              void* d_out, int out_size, void* d_ws, size_t ws_size,
                              hipStream_t stream) {
  (void)in_sizes; (void)n_in; (void)out_size; (void)ws_size;
  const int*   diag  = (const int*)d_in[0];
  const float* mask  = (const float*)d_in[1];
  const float* table = (const float*)d_in[2];
  const float* Wih   = (const float*)d_in[3];
  const float* Whh   = (const float*)d_in[4];
  const float* bih   = (const float*)d_in[5];
  const float* bhh   = (const float*)d_in[6];
  const float* fcw   = (const float*)d_in[7];
  const float* fcb   = (const float*)d_in[8];

  float* ws       = (float*)d_ws;
  float* sumembed = ws + OFF_SUM;
  float* pre      = ws + OFF_PRE;
  float* truh     = ws + OFF_TRUH;
  int*   last     = (int*)(ws + OFF_LAST);
  float* out      = (float*)d_out;

  hipMemsetAsync(last, 0, NB * sizeof(int), stream);
  k_embed  <<<dim3(NB * NV), dim3(128), 0, stream>>>(diag, mask, table, sumembed, last);
  k_pregemm<<<dim3(512, 7),  dim3(256), 0, stream>>>(sumembed, Wih, bih, bhh, pre);
  k_lstm   <<<dim3(NE),      dim3(448), 0, stream>>>(pre, Whh, last, truh);
  k_fc     <<<dim3(NB),      dim3(128), 0, stream>>>(truh, fcw, fcb, out);
}

// Round 3
// 558.720 us; speedup vs baseline: 1.0753x; 1.0753x over previous
//
#include <hip/hip_runtime.h>
#include <math.h>

#define NB 256      // batch / time steps
#define NV 100      // visits
#define NC 40       // codes per visit
#define NE 128      // embed dim (LSTM "batch")
#define NH 100      // hidden (== feat)
#define NG 400      // 4*NH

// ws layout (float elements)
#define OFF_SUM   0
#define N_SUM     (NB*NV*NE)                 // 3,276,800  (x2 viewed [32768][100])
#define OFF_PRE   (OFF_SUM + N_SUM)
#define N_PRE     (NB*NE*NG)                 // 13,107,200
#define OFF_TRUH  (OFF_PRE + N_PRE)
#define N_TRUH    (NB*NE)                    // 32,768
#define OFF_LAST  (OFF_TRUH + N_TRUH)        // ints, 256

// ---------------------------------------------------------------- kernel 1
// masked embedding sum  +  last-visit segment max
__global__ __launch_bounds__(128) void k_embed(
    const int* __restrict__ diag, const float* __restrict__ mask,
    const float* __restrict__ table, float* __restrict__ sumembed,
    int* __restrict__ last) {
  int bv = blockIdx.x;              // 0..25599
  int b  = bv / NV;
  int v  = bv - b * NV;
  int base = bv * NC;
  int e = threadIdx.x;              // 0..127
  float acc = 0.f;
  float msum = 0.f;
  for (int c = 0; c < NC; ++c) {
    float m = mask[base + c];       // wave-uniform -> scalar load
    msum += m;
    if (m != 0.f) {                 // uniform branch, skips dead gathers
      int idx = diag[base + c];     // wave-uniform
      acc = fmaf(m, table[idx * NE + e], acc);
    }
  }
  sumembed[bv * NE + e] = acc;
  if (e == 0 && msum > 0.f) atomicMax(&last[b], v);
}

// ---------------------------------------------------------------- kernel 2
// pre[t*128+e][c] = x2[m][:] . W_ih[j(c)][:] + bias[j(c)]
// M=32768, K=100, N=400.  64x64 tiles, 4x4 register tiles.
// COLUMN PERMUTATION for k_lstm's 2-rows-per-thread map: column
// c = 4*u + 2*q + s  holds gate row  j = s*200 + q*100 + u, so that
// k_lstm thread tid (u=tid>>1, q=tid&1) loads its two rows as ONE
// coalesced float2 at pre[..][2*tid]. Per-value math identical.
__global__ __launch_bounds__(256) void k_pregemm(
    const float* __restrict__ x2, const float* __restrict__ Wih,
    const float* __restrict__ bih, const float* __restrict__ bhh,
    float* __restrict__ pre) {
  __shared__ __align__(16) float As[100][68];   // [k][m], stride 68 => 16B aligned rows
  __shared__ __align__(16) float Bs[100][68];   // [k][n]
  __shared__ __align__(16) float bias_s[64];
  const int m0 = blockIdx.x * 64;
  const int n0 = blockIdx.y * 64;
  const int tid = threadIdx.x;

  for (int idx = tid; idx < 6400; idx += 256) {
    int m = idx / 100, k = idx - m * 100;
    As[k][m] = x2[(m0 + m) * 100 + k];          // coalesced along k
  }
  for (int idx = tid; idx < 6400; idx += 256) {
    int n = idx / 100, k = idx - n * 100;
    int q = n0 + n;                             // permuted output col
    int j = (q & 1) * 200 + ((q >> 1) & 1) * 100 + (q >> 2);  // gate row
    Bs[k][n] = (q < NG) ? Wih[j * 100 + k] : 0.f;
  }
  if (tid < 64) {
    int q = n0 + tid;
    int j = (q & 1) * 200 + ((q >> 1) & 1) * 100 + (q >> 2);
    bias_s[tid] = (q < NG) ? (bih[j] + bhh[j]) : 0.f;
  }
  __syncthreads();

  const int tm = tid & 15, tn = tid >> 4;       // 16x16 thread grid, 4x4 each
  float acc[4][4] = {};
  #pragma unroll 4
  for (int k = 0; k < 100; ++k) {
    float4 a  = *(const float4*)&As[k][tm * 4];
    float4 bb = *(const float4*)&Bs[k][tn * 4];
    acc[0][0] = fmaf(a.x, bb.x, acc[0][0]); acc[0][1] = fmaf(a.x, bb.y, acc[0][1]);
    acc[0][2] = fmaf(a.x, bb.z, acc[0][2]); acc[0][3] = fmaf(a.x, bb.w, acc[0][3]);
    acc[1][0] = fmaf(a.y, bb.x, acc[1][0]); acc[1][1] = fmaf(a.y, bb.y, acc[1][1]);
    acc[1][2] = fmaf(a.y, bb.z, acc[1][2]); acc[1][3] = fmaf(a.y, bb.w, acc[1][3]);
    acc[2][0] = fmaf(a.z, bb.x, acc[2][0]); acc[2][1] = fmaf(a.z, bb.y, acc[2][1]);
    acc[2][2] = fmaf(a.z, bb.z, acc[2][2]); acc[2][3] = fmaf(a.z, bb.w, acc[2][3]);
    acc[3][0] = fmaf(a.w, bb.x, acc[3][0]); acc[3][1] = fmaf(a.w, bb.y, acc[3][1]);
    acc[3][2] = fmaf(a.w, bb.z, acc[3][2]); acc[3][3] = fmaf(a.w, bb.w, acc[3][3]);
  }

  if (n0 + tn * 4 < NG) {                       // whole float4 valid or none (400%4==0)
    float4 bb = *(const float4*)&bias_s[tn * 4];
    #pragma unroll
    for (int im = 0; im < 4; ++im) {
      int m = m0 + tm * 4 + im;
      float4 st;
      st.x = acc[im][0] + bb.x; st.y = acc[im][1] + bb.y;
      st.z = acc[im][2] + bb.z; st.w = acc[im][3] + bb.w;
      *(float4*)&pre[m * NG + n0 + tn * 4] = st;
    }
  }
}

// ---------------------------------------------------------------- kernel 3
// sequential LSTM, 128 blocks x 256 threads (4 waves), TWO gate rows per
// thread: tid -> u=tid>>1, q=tid&1; rows rA=q*100+u (i or f) and
// rB=200+q*100+u (g or o). 200 weight VGPRs/thread.
//
// R1/R2 POST-MORTEM CALIBRATION: step cost ~= (#LDS instr per CU) x
// ~9.4cyc. R0: 200 b128 -> 2060cyc. R1: 175 b128 + 21 bpermute -> 2197.
// R2 readlane (SGPR-write hazards + AGPR traffic) -> 3120. This version:
// 4 waves x 25 b128 = 100 broadcast reads (~940cyc) and the gate
// exchange is ONE __shfl_xor(.,1) == quad-perm DPP (pure VALU, no LDS),
// replacing g_s roundtrip / 3 bpermutes. Single barrier per step with
// double-buffered h (write buf (t+1)&1, read buf t&1).
__device__ __forceinline__ float fast_sigmoid(float x) {
  return 1.f / (1.f + __expf(-x));
}
__device__ __forceinline__ float fast_tanh(float x) {
  float ax = fabsf(x);
  float e  = __expf(-2.f * ax);
  float t  = (1.f - e) / (1.f + e);
  return x < 0.f ? -t : t;
}

#define FMA4(A, W, H)                                                     \
  A = fmaf((H).x, (W).x, A); A = fmaf((H).y, (W).y, A);                   \
  A = fmaf((H).z, (W).z, A); A = fmaf((H).w, (W).w, A)

__global__ __launch_bounds__(256, 1) void k_lstm(
    const float* __restrict__ pre, const float* __restrict__ Whh,
    const int* __restrict__ last, float* __restrict__ truh) {
  __shared__ __align__(16) float hbuf[2][100];  // 400B rows -> [1] stays 16B aligned
  __shared__ int last_s[NB];
  const int e = blockIdx.x;         // 0..127
  const int tid = threadIdx.x;      // active < 200
  const int uu = tid >> 1;          // unclamped unit
  const int q  = tid & 1;
  const int u  = (uu < NH) ? uu : (NH - 1);     // clamped for tid>=200
  const int rA = q * 100 + u;       // i (q=0) or f (q=1)
  const int rB = 200 + q * 100 + u; // g (q=0) or o (q=1)
  const int tidc = (tid < 200) ? tid : 199;     // clamped pre column pair

  // 2 x 25 named float4 = 200 weight VGPRs. Row stride 400B -> 16B aligned.
  const float4* wra = (const float4*)(Whh + rA * 100);
  const float4* wrb = (const float4*)(Whh + rB * 100);
  float4 wa00 = wra[0],  wa01 = wra[1],  wa02 = wra[2],  wa03 = wra[3],
         wa04 = wra[4],  wa05 = wra[5],  wa06 = wra[6],  wa07 = wra[7],
         wa08 = wra[8],  wa09 = wra[9],  wa10 = wra[10], wa11 = wra[11],
         wa12 = wra[12], wa13 = wra[13], wa14 = wra[14], wa15 = wra[15],
         wa16 = wra[16], wa17 = wra[17], wa18 = wra[18], wa19 = wra[19],
         wa20 = wra[20], wa21 = wra[21], wa22 = wra[22], wa23 = wra[23],
         wa24 = wra[24];
  float4 wb00 = wrb[0],  wb01 = wrb[1],  wb02 = wrb[2],  wb03 = wrb[3],
         wb04 = wrb[4],  wb05 = wrb[5],  wb06 = wrb[6],  wb07 = wrb[7],
         wb08 = wrb[8],  wb09 = wrb[9],  wb10 = wrb[10], wb11 = wrb[11],
         wb12 = wrb[12], wb13 = wrb[13], wb14 = wrb[14], wb15 = wrb[15],
         wb16 = wrb[16], wb17 = wrb[17], wb18 = wrb[18], wb19 = wrb[19],
         wb20 = wrb[20], wb21 = wrb[21], wb22 = wrb[22], wb23 = wrb[23],
         wb24 = wrb[24];

  if (tid < NH) { hbuf[0][tid] = 0.f; hbuf[1][tid] = 0.f; }
  last_s[tid] = last[tid];          // blockDim == NB == 256
  float c = 0.f;                    // cell state lives in q==1 lanes

  // pre column pair == 2*tid (k_pregemm stores the permuted order)
  const float* pbase = pre + e * NG + 2 * tidc;   // + t*51200 per step
  float2 p0 = *(const float2*)(pbase);
  float2 p1 = *(const float2*)(pbase + 51200);
  float2 p2 = *(const float2*)(pbase + 2 * 51200);
  __syncthreads();

  for (int t = 0; t < NB; ++t) {
    float2 p3;
    if (t + 3 < NB) p3 = *(const float2*)(pbase + (t + 3) * 51200);
    else            { p3.x = 0.f; p3.y = 0.f; }

    // GEMV: both rows share each h float4 (one b128 feeds 8 FMAs).
    // Same 4-chain ladder + reduction order per row as R0/R1 -> bit-identical.
    float a0 = p0.x, a1 = 0.f, a2 = 0.f, a3 = 0.f;
    float b0 = p0.y, b1 = 0.f, b2 = 0.f, b3 = 0.f;
    const float4* h4 = (const float4*)hbuf[t & 1];
    float4 h;
    h = h4[0];  FMA4(a0, wa00, h); FMA4(b0, wb00, h);
    h = h4[1];  FMA4(a1, wa01, h); FMA4(b1, wb01, h);
    h = h4[2];  FMA4(a2, wa02, h); FMA4(b2, wb02, h);
    h = h4[3];  FMA4(a3, wa03, h); FMA4(b3, wb03, h);
    h = h4[4];  FMA4(a0, wa04, h); FMA4(b0, wb04, h);
    h = h4[5];  FMA4(a1, wa05, h); FMA4(b1, wb05, h);
    h = h4[6];  FMA4(a2, wa06, h); FMA4(b2, wb06, h);
    h = h4[7];  FMA4(a3, wa07, h); FMA4(b3, wb07, h);
    h = h4[8];  FMA4(a0, wa08, h); FMA4(b0, wb08, h);
    h = h4[9];  FMA4(a1, wa09, h); FMA4(b1, wb09, h);
    h = h4[10]; FMA4(a2, wa10, h); FMA4(b2, wb10, h);
    h = h4[11]; FMA4(a3, wa11, h); FMA4(b3, wb11, h);
    h = h4[12]; FMA4(a0, wa12, h); FMA4(b0, wb12, h);
    h = h4[13]; FMA4(a1, wa13, h); FMA4(b1, wb13, h);
    h = h4[14]; FMA4(a2, wa14, h); FMA4(b2, wb14, h);
    h = h4[15]; FMA4(a3, wa15, h); FMA4(b3, wb15, h);
    h = h4[16]; FMA4(a0, wa16, h); FMA4(b0, wb16, h);
    h = h4[17]; FMA4(a1, wa17, h); FMA4(b1, wb17, h);
    h = h4[18]; FMA4(a2, wa18, h); FMA4(b2, wb18, h);
    h = h4[19]; FMA4(a3, wa19, h); FMA4(b3, wb19, h);
    h = h4[20]; FMA4(a0, wa20, h); FMA4(b0, wb20, h);
    h = h4[21]; FMA4(a1, wa21, h); FMA4(b1, wb21, h);
    h = h4[22]; FMA4(a2, wa22, h); FMA4(b2, wb22, h);
    h = h4[23]; FMA4(a3, wa23, h); FMA4(b3, wb23, h);
    h = h4[24]; FMA4(a0, wa24, h); FMA4(b0, wb24, h);
    float accA = (a0 + a1) + (a2 + a3);           // i (q=0) / f (q=1)
    float accB = (b0 + b1) + (b2 + b3);           // g (q=0) / o (q=1)

    float actA = fast_sigmoid(accA);              // i and f: both sigmoid
    float actB = (q == 0) ? fast_tanh(accB) : fast_sigmoid(accB); // g / o
    float prod = actA * actB;                     // q=0: i*g (q=1: unused)
    float ig = __shfl_xor(prod, 1);               // quad-perm DPP, no LDS

    if (q == 1 && uu < NH) {                      // actA==f, actB==o here
      c = fmaf(actA, c, ig);
      float hv = actB * fast_tanh(c);
      hbuf[(t + 1) & 1][uu] = hv;
      if (uu == last_s[t]) truh[t * NE + e] = hv; // hs[b=t, e, last[t]]
    }
    __syncthreads();                  // h(t+1) visible; step-t reads drained
    p0 = p1; p1 = p2; p2 = p3;
  }
}

// ---------------------------------------------------------------- kernel 4
// out[b] = sigmoid( truh[b,:] . fc_w + fc_b )
__global__ __launch_bounds__(128) void k_fc(
    const float* __restrict__ truh, const float* __restrict__ fcw,
    const float* __restrict__ fcb, float* __restrict__ out) {
  int b = blockIdx.x, t = threadIdx.x;
  float v = truh[b * NE + t] * fcw[t];
  #pragma unroll
  for (int o = 32; o > 0; o >>= 1) v += __shfl_down(v, o);
  __shared__ float s[2];
  if ((t & 63) == 0) s[t >> 6] = v;
  __syncthreads();
  if (t == 0) {
    float sum = s[0] + s[1] + fcb[0];
    out[b] = 1.f / (1.f + __expf(-sum));
  }
}

// ---------------------------------------------------------------- launch
extern "C" void kernel_launch(void* const* d_in, const int* in_sizes, int n_in,
                              void* d_out, int out_size, void* d_ws, size_t ws_size,
                              hipStream_t stream) {
  (void)in_sizes; (void)n_in; (void)out_size; (void)ws_size;
  const int*   diag  = (const int*)d_in[0];
  const float* mask  = (const float*)d_in[1];
  const float* table = (const float*)d_in[2];
  const float* Wih   = (const float*)d_in[3];
  const float* Whh   = (const float*)d_in[4];
  const float* bih   = (const float*)d_in[5];
  const float* bhh   = (const float*)d_in[6];
  const float* fcw   = (const float*)d_in[7];
  const float* fcb   = (const float*)d_in[8];

  float* ws       = (float*)d_ws;
  float* sumembed = ws + OFF_SUM;
  float* pre      = ws + OFF_PRE;
  float* truh     = ws + OFF_TRUH;
  int*   last     = (int*)(ws + OFF_LAST);
  float* out      = (float*)d_out;

  hipMemsetAsync(last, 0, NB * sizeof(int), stream);
  k_embed  <<<dim3(NB * NV), dim3(128), 0, stream>>>(diag, mask, table, sumembed, last);
  k_pregemm<<<dim3(512, 7),  dim3(256), 0, stream>>>(sumembed, Wih, bih, bhh, pre);
  k_lstm   <<<dim3(NE),      dim3(256), 0, stream>>>(pre, Whh, last, truh);
  k_fc     <<<dim3(NB),      dim3(128), 0, stream>>>(truh, fcw, fcb, out);
}

// Round 4
// 518.065 us; speedup vs baseline: 1.1597x; 1.0785x over previous
//
#include <hip/hip_runtime.h>
#include <math.h>

#define NB 256      // batch / time steps
#define NV 100      // visits
#define NC 40       // codes per visit
#define NE 128      // embed dim (LSTM "batch")
#define NH 100      // hidden (== feat)
#define NG 400      // 4*NH

// ws layout (float elements)
#define OFF_SUM   0
#define N_SUM     (NB*NV*NE)                 // 3,276,800  (x2 viewed [32768][100])
#define OFF_PRE   (OFF_SUM + N_SUM)
#define N_PRE     (NB*NE*NG)                 // 13,107,200
#define OFF_TRUH  (OFF_PRE + N_PRE)
#define N_TRUH    (NB*NE)                    // 32,768
#define OFF_LAST  (OFF_TRUH + N_TRUH)        // ints, 256

// ---------------------------------------------------------------- kernel 1
// masked embedding sum + last-visit segment max.
// R4: stage the 40 mask/diag values in LDS first (one coalesced phase),
// then 40 branch-free gathers whose addresses are all known up front ->
// loads pipeline instead of the old 40-deep dependent chain
// (uniform-load -> branch -> uniform-load -> gather per iteration).
// Numerics: single acc chain in ascending c, and fmaf(0,t,acc)==acc
// bit-exactly (acc never -0, table finite) -> identical to masked-skip.
__global__ __launch_bounds__(128) void k_embed(
    const int* __restrict__ diag, const float* __restrict__ mask,
    const float* __restrict__ table, float* __restrict__ sumembed,
    int* __restrict__ last) {
  __shared__ float m_s[NC];
  __shared__ int   d_s[NC];
  int bv = blockIdx.x;              // 0..25599
  int b  = bv / NV;
  int v  = bv - b * NV;
  int base = bv * NC;
  int e = threadIdx.x;              // 0..127
  if (e < NC) { m_s[e] = mask[base + e]; d_s[e] = diag[base + e]; }
  __syncthreads();

  float acc = 0.f;
  float msum = 0.f;
  #pragma unroll
  for (int c = 0; c < NC; ++c) {
    float m = m_s[c];               // LDS broadcast, cheap
    int idx = d_s[c];
    acc = fmaf(m, table[idx * NE + e], acc);   // gathers independent -> MLP
    msum += m;
  }
  sumembed[bv * NE + e] = acc;
  if (e == 0 && msum > 0.f) atomicMax(&last[b], v);
}

// ---------------------------------------------------------------- kernel 2
// pre[t*128+e][c] = x2[m][:] . W_ih[j(c)][:] + bias[j(c)]
// M=32768, K=100, N=400.  64x64 tiles, 4x4 register tiles.
// COLUMN PERMUTATION for k_lstm's 2-rows-per-thread map: column
// c = 4*u + 2*q + s  holds gate row  j = s*200 + q*100 + u, so that
// k_lstm thread tid (u=tid>>1, q=tid&1) loads its two rows as ONE
// coalesced float2 at pre[..][2*tid]. Per-value math identical.
__global__ __launch_bounds__(256) void k_pregemm(
    const float* __restrict__ x2, const float* __restrict__ Wih,
    const float* __restrict__ bih, const float* __restrict__ bhh,
    float* __restrict__ pre) {
  __shared__ __align__(16) float As[100][68];   // [k][m], stride 68 => 16B aligned rows
  __shared__ __align__(16) float Bs[100][68];   // [k][n]
  __shared__ __align__(16) float bias_s[64];
  const int m0 = blockIdx.x * 64;
  const int n0 = blockIdx.y * 64;
  const int tid = threadIdx.x;

  for (int idx = tid; idx < 6400; idx += 256) {
    int m = idx / 100, k = idx - m * 100;
    As[k][m] = x2[(m0 + m) * 100 + k];          // coalesced along k
  }
  for (int idx = tid; idx < 6400; idx += 256) {
    int n = idx / 100, k = idx - n * 100;
    int q = n0 + n;                             // permuted output col
    int j = (q & 1) * 200 + ((q >> 1) & 1) * 100 + (q >> 2);  // gate row
    Bs[k][n] = (q < NG) ? Wih[j * 100 + k] : 0.f;
  }
  if (tid < 64) {
    int q = n0 + tid;
    int j = (q & 1) * 200 + ((q >> 1) & 1) * 100 + (q >> 2);
    bias_s[tid] = (q < NG) ? (bih[j] + bhh[j]) : 0.f;
  }
  __syncthreads();

  const int tm = tid & 15, tn = tid >> 4;       // 16x16 thread grid, 4x4 each
  float acc[4][4] = {};
  #pragma unroll 4
  for (int k = 0; k < 100; ++k) {
    float4 a  = *(const float4*)&As[k][tm * 4];
    float4 bb = *(const float4*)&Bs[k][tn * 4];
    acc[0][0] = fmaf(a.x, bb.x, acc[0][0]); acc[0][1] = fmaf(a.x, bb.y, acc[0][1]);
    acc[0][2] = fmaf(a.x, bb.z, acc[0][2]); acc[0][3] = fmaf(a.x, bb.w, acc[0][3]);
    acc[1][0] = fmaf(a.y, bb.x, acc[1][0]); acc[1][1] = fmaf(a.y, bb.y, acc[1][1]);
    acc[1][2] = fmaf(a.y, bb.z, acc[1][2]); acc[1][3] = fmaf(a.y, bb.w, acc[1][3]);
    acc[2][0] = fmaf(a.z, bb.x, acc[2][0]); acc[2][1] = fmaf(a.z, bb.y, acc[2][1]);
    acc[2][2] = fmaf(a.z, bb.z, acc[2][2]); acc[2][3] = fmaf(a.z, bb.w, acc[2][3]);
    acc[3][0] = fmaf(a.w, bb.x, acc[3][0]); acc[3][1] = fmaf(a.w, bb.y, acc[3][1]);
    acc[3][2] = fmaf(a.w, bb.z, acc[3][2]); acc[3][3] = fmaf(a.w, bb.w, acc[3][3]);
  }

  if (n0 + tn * 4 < NG) {                       // whole float4 valid or none (400%4==0)
    float4 bb = *(const float4*)&bias_s[tn * 4];
    #pragma unroll
    for (int im = 0; im < 4; ++im) {
      int m = m0 + tm * 4 + im;
      float4 st;
      st.x = acc[im][0] + bb.x; st.y = acc[im][1] + bb.y;
      st.z = acc[im][2] + bb.z; st.w = acc[im][3] + bb.w;
      *(float4*)&pre[m * NG + n0 + tn * 4] = st;
    }
  }
}

// ---------------------------------------------------------------- kernel 3
// sequential LSTM, 128 blocks x 256 threads (4 waves), TWO gate rows per
// thread (R3 mapping: u=tid>>1, q=tid&1; rows q*100+u and 200+q*100+u).
//
// R3 POST-MORTEM: halving LDS reads to 100 regressed because under 200+
// live weight floats the compiler stopped prefetching h-reads -> 25 x
// (exposed ds_read latency ~105cyc) = 2662cyc/step, and 1 wave/SIMD hid
// nothing. R4 FIX: EXPLICIT 4-deep rotating h prefetch (hA..hD). Group k
// uses buffer k%4 and immediately reloads it with h4[k+4] -> read->use
// distance = 4 groups (~96 VALU cyc), a data dependence the scheduler
// cannot undo. Same FMA chains/order as R3 -> bit-identical output.
__device__ __forceinline__ float fast_sigmoid(float x) {
  return 1.f / (1.f + __expf(-x));
}
__device__ __forceinline__ float fast_tanh(float x) {
  float ax = fabsf(x);
  float e  = __expf(-2.f * ax);
  float t  = (1.f - e) / (1.f + e);
  return x < 0.f ? -t : t;
}

#define FMA4(A, W, H)                                                     \
  A = fmaf((H).x, (W).x, A); A = fmaf((H).y, (W).y, A);                   \
  A = fmaf((H).z, (W).z, A); A = fmaf((H).w, (W).w, A)

__global__ __launch_bounds__(256, 1) void k_lstm(
    const float* __restrict__ pre, const float* __restrict__ Whh,
    const int* __restrict__ last, float* __restrict__ truh) {
  __shared__ __align__(16) float hbuf[2][100];  // 400B rows -> [1] stays 16B aligned
  __shared__ int last_s[NB];
  const int e = blockIdx.x;         // 0..127
  const int tid = threadIdx.x;      // active < 200
  const int uu = tid >> 1;          // unclamped unit
  const int q  = tid & 1;
  const int u  = (uu < NH) ? uu : (NH - 1);     // clamped for tid>=200
  const int rA = q * 100 + u;       // i (q=0) or f (q=1)
  const int rB = 200 + q * 100 + u; // g (q=0) or o (q=1)
  const int tidc = (tid < 200) ? tid : 199;     // clamped pre column pair

  // 2 x 25 named float4 = 200 weight floats. Row stride 400B -> 16B aligned.
  const float4* wra = (const float4*)(Whh + rA * 100);
  const float4* wrb = (const float4*)(Whh + rB * 100);
  float4 wa00 = wra[0],  wa01 = wra[1],  wa02 = wra[2],  wa03 = wra[3],
         wa04 = wra[4],  wa05 = wra[5],  wa06 = wra[6],  wa07 = wra[7],
         wa08 = wra[8],  wa09 = wra[9],  wa10 = wra[10], wa11 = wra[11],
         wa12 = wra[12], wa13 = wra[13], wa14 = wra[14], wa15 = wra[15],
         wa16 = wra[16], wa17 = wra[17], wa18 = wra[18], wa19 = wra[19],
         wa20 = wra[20], wa21 = wra[21], wa22 = wra[22], wa23 = wra[23],
         wa24 = wra[24];
  float4 wb00 = wrb[0],  wb01 = wrb[1],  wb02 = wrb[2],  wb03 = wrb[3],
         wb04 = wrb[4],  wb05 = wrb[5],  wb06 = wrb[6],  wb07 = wrb[7],
         wb08 = wrb[8],  wb09 = wrb[9],  wb10 = wrb[10], wb11 = wrb[11],
         wb12 = wrb[12], wb13 = wrb[13], wb14 = wrb[14], wb15 = wrb[15],
         wb16 = wrb[16], wb17 = wrb[17], wb18 = wrb[18], wb19 = wrb[19],
         wb20 = wrb[20], wb21 = wrb[21], wb22 = wrb[22], wb23 = wrb[23],
         wb24 = wrb[24];

  if (tid < NH) { hbuf[0][tid] = 0.f; hbuf[1][tid] = 0.f; }
  last_s[tid] = last[tid];          // blockDim == NB == 256
  float c = 0.f;                    // cell state lives in q==1 lanes

  // pre column pair == 2*tid (k_pregemm stores the permuted order)
  const float* pbase = pre + e * NG + 2 * tidc;   // + t*51200 per step
  float2 p0 = *(const float2*)(pbase);
  float2 p1 = *(const float2*)(pbase + 51200);
  float2 p2 = *(const float2*)(pbase + 2 * 51200);
  __syncthreads();

  for (int t = 0; t < NB; ++t) {
    float2 p3;
    if (t + 3 < NB) p3 = *(const float2*)(pbase + (t + 3) * 51200);
    else            { p3.x = 0.f; p3.y = 0.f; }

    // GEMV with explicit 4-deep h pipeline. Chain/order == R3.
    float a0 = p0.x, a1 = 0.f, a2 = 0.f, a3 = 0.f;
    float b0 = p0.y, b1 = 0.f, b2 = 0.f, b3 = 0.f;
    const float4* h4 = (const float4*)hbuf[t & 1];
    float4 hA = h4[0], hB = h4[1], hC = h4[2], hD = h4[3];
    FMA4(a0, wa00, hA); FMA4(b0, wb00, hA); hA = h4[4];
    FMA4(a1, wa01, hB); FMA4(b1, wb01, hB); hB = h4[5];
    FMA4(a2, wa02, hC); FMA4(b2, wb02, hC); hC = h4[6];
    FMA4(a3, wa03, hD); FMA4(b3, wb03, hD); hD = h4[7];
    FMA4(a0, wa04, hA); FMA4(b0, wb04, hA); hA = h4[8];
    FMA4(a1, wa05, hB); FMA4(b1, wb05, hB); hB = h4[9];
    FMA4(a2, wa06, hC); FMA4(b2, wb06, hC); hC = h4[10];
    FMA4(a3, wa07, hD); FMA4(b3, wb07, hD); hD = h4[11];
    FMA4(a0, wa08, hA); FMA4(b0, wb08, hA); hA = h4[12];
    FMA4(a1, wa09, hB); FMA4(b1, wb09, hB); hB = h4[13];
    FMA4(a2, wa10, hC); FMA4(b2, wb10, hC); hC = h4[14];
    FMA4(a3, wa11, hD); FMA4(b3, wb11, hD); hD = h4[15];
    FMA4(a0, wa12, hA); FMA4(b0, wb12, hA); hA = h4[16];
    FMA4(a1, wa13, hB); FMA4(b1, wb13, hB); hB = h4[17];
    FMA4(a2, wa14, hC); FMA4(b2, wb14, hC); hC = h4[18];
    FMA4(a3, wa15, hD); FMA4(b3, wb15, hD); hD = h4[19];
    FMA4(a0, wa16, hA); FMA4(b0, wb16, hA); hA = h4[20];
    FMA4(a1, wa17, hB); FMA4(b1, wb17, hB); hB = h4[21];
    FMA4(a2, wa18, hC); FMA4(b2, wb18, hC); hC = h4[22];
    FMA4(a3, wa19, hD); FMA4(b3, wb19, hD); hD = h4[23];
    FMA4(a0, wa20, hA); FMA4(b0, wb20, hA); hA = h4[24];
    FMA4(a1, wa21, hB); FMA4(b1, wb21, hB);
    FMA4(a2, wa22, hC); FMA4(b2, wb22, hC);
    FMA4(a3, wa23, hD); FMA4(b3, wb23, hD);
    FMA4(a0, wa24, hA); FMA4(b0, wb24, hA);
    float accA = (a0 + a1) + (a2 + a3);           // i (q=0) / f (q=1)
    float accB = (b0 + b1) + (b2 + b3);           // g (q=0) / o (q=1)

    float actA = fast_sigmoid(accA);              // i and f: both sigmoid
    float actB = (q == 0) ? fast_tanh(accB) : fast_sigmoid(accB); // g / o
    float prod = actA * actB;                     // q=0: i*g (q=1: unused)
    float ig = __shfl_xor(prod, 1);               // quad-perm DPP, no LDS

    if (q == 1 && uu < NH) {                      // actA==f, actB==o here
      c = fmaf(actA, c, ig);
      float hv = actB * fast_tanh(c);
      hbuf[(t + 1) & 1][uu] = hv;
      if (uu == last_s[t]) truh[t * NE + e] = hv; // hs[b=t, e, last[t]]
    }
    __syncthreads();                  // h(t+1) visible; step-t reads drained
    p0 = p1; p1 = p2; p2 = p3;
  }
}

// ---------------------------------------------------------------- kernel 4
// out[b] = sigmoid( truh[b,:] . fc_w + fc_b )
__global__ __launch_bounds__(128) void k_fc(
    const float* __restrict__ truh, const float* __restrict__ fcw,
    const float* __restrict__ fcb, float* __restrict__ out) {
  int b = blockIdx.x, t = threadIdx.x;
  float v = truh[b * NE + t] * fcw[t];
  #pragma unroll
  for (int o = 32; o > 0; o >>= 1) v += __shfl_down(v, o);
  __shared__ float s[2];
  if ((t & 63) == 0) s[t >> 6] = v;
  __syncthreads();
  if (t == 0) {
    float sum = s[0] + s[1] + fcb[0];
    out[b] = 1.f / (1.f + __expf(-sum));
  }
}

// ---------------------------------------------------------------- launch
extern "C" void kernel_launch(void* const* d_in, const int* in_sizes, int n_in,
                              void* d_out, int out_size, void* d_ws, size_t ws_size,
                              hipStream_t stream) {
  (void)in_sizes; (void)n_in; (void)out_size; (void)ws_size;
  const int*   diag  = (const int*)d_in[0];
  const float* mask  = (const float*)d_in[1];
  const float* table = (const float*)d_in[2];
  const float* Wih   = (const float*)d_in[3];
  const float* Whh   = (const float*)d_in[4];
  const float* bih   = (const float*)d_in[5];
  const float* bhh   = (const float*)d_in[6];
  const float* fcw   = (const float*)d_in[7];
  const float* fcb   = (const float*)d_in[8];

  float* ws       = (float*)d_ws;
  float* sumembed = ws + OFF_SUM;
  float* pre      = ws + OFF_PRE;
  float* truh     = ws + OFF_TRUH;
  int*   last     = (int*)(ws + OFF_LAST);
  float* out      = (float*)d_out;

  hipMemsetAsync(last, 0, NB * sizeof(int), stream);
  k_embed  <<<dim3(NB * NV), dim3(128), 0, stream>>>(diag, mask, table, sumembed, last);
  k_pregemm<<<dim3(512, 7),  dim3(256), 0, stream>>>(sumembed, Wih, bih, bhh, pre);
  k_lstm   <<<dim3(NE),      dim3(256), 0, stream>>>(pre, Whh, last, truh);
  k_fc     <<<dim3(NB),      dim3(128), 0, stream>>>(truh, fcw, fcb, out);
}

// Round 5
// 438.312 us; speedup vs baseline: 1.3707x; 1.1820x over previous
//
#include <hip/hip_runtime.h>
#include <math.h>

#define NB 256      // batch / time steps
#define NV 100      // visits
#define NC 40       // codes per visit
#define NE 128      // embed dim (LSTM "batch")
#define NH 100      // hidden (== feat)
#define NG 400      // 4*NH

// ws layout (float elements)
#define OFF_SUM   0
#define N_SUM     (NB*NV*NE)                 // 3,276,800  (x2 viewed [32768][100])
#define OFF_PRE   (OFF_SUM + N_SUM)
#define N_PRE     (NB*NE*NG)                 // 13,107,200
#define OFF_TRUH  (OFF_PRE + N_PRE)
#define N_TRUH    (NB*NE)                    // 32,768
#define OFF_LAST  (OFF_TRUH + N_TRUH)        // ints, 256

// ---------------------------------------------------------------- kernel 1
// masked embedding sum + last-visit segment max. (R4 version - it helped:
// stage 40 mask/diag in LDS, then branch-free independent gathers.)
__global__ __launch_bounds__(128) void k_embed(
    const int* __restrict__ diag, const float* __restrict__ mask,
    const float* __restrict__ table, float* __restrict__ sumembed,
    int* __restrict__ last) {
  __shared__ float m_s[NC];
  __shared__ int   d_s[NC];
  int bv = blockIdx.x;              // 0..25599
  int b  = bv / NV;
  int v  = bv - b * NV;
  int base = bv * NC;
  int e = threadIdx.x;              // 0..127
  if (e < NC) { m_s[e] = mask[base + e]; d_s[e] = diag[base + e]; }
  __syncthreads();

  float acc = 0.f;
  float msum = 0.f;
  #pragma unroll
  for (int c = 0; c < NC; ++c) {
    float m = m_s[c];               // LDS broadcast, cheap
    int idx = d_s[c];
    acc = fmaf(m, table[idx * NE + e], acc);   // gathers independent -> MLP
    msum += m;
  }
  sumembed[bv * NE + e] = acc;
  if (e == 0 && msum > 0.f) atomicMax(&last[b], v);
}

// ---------------------------------------------------------------- kernel 2
// pre[t*128+e][j] = x2[m][:] . W_ih[j][:] + (b_ih[j]+b_hh[j])
// M=32768, K=100, N=400. R5: 128x64 tiles, 8Mx4N per thread (M split as
// tm*4 and 64+tm*4 so A-reads stay 2-way bank-aliased = free). vs the
// old 64x64/4x4: 25% fewer loop LDS instrs per FMA and HALF the blocks
// -> half the staging (8-way-conflict writes) and half the x2 re-reads.
// Per-output math: same single k-ascending FMA chain, bias at store ->
// bit-identical. Output is UNPERMUTED gate rows (k_lstm R0 layout).
__global__ __launch_bounds__(256) void k_pregemm(
    const float* __restrict__ x2, const float* __restrict__ Wih,
    const float* __restrict__ bih, const float* __restrict__ bhh,
    float* __restrict__ pre) {
  __shared__ __align__(16) float As[100][132];  // [k][m], 128 + 4 pad (16B rows)
  __shared__ __align__(16) float Bs[100][68];   // [k][n], 64 + 4 pad
  __shared__ __align__(16) float bias_s[64];
  const int m0 = blockIdx.x * 128;
  const int n0 = blockIdx.y * 64;
  const int tid = threadIdx.x;

  for (int idx = tid; idx < 12800; idx += 256) {  // A: 128 rows x 100 k
    int m = idx / 100, k = idx - m * 100;
    As[k][m] = x2[(m0 + m) * 100 + k];            // coalesced along k
  }
  for (int idx = tid; idx < 6400; idx += 256) {   // B: 64 rows x 100 k
    int n = idx / 100, k = idx - n * 100;
    int j = n0 + n;
    Bs[k][n] = (j < NG) ? Wih[j * 100 + k] : 0.f;
  }
  if (tid < 64) {
    int j = n0 + tid;
    bias_s[tid] = (j < NG) ? (bih[j] + bhh[j]) : 0.f;
  }
  __syncthreads();

  const int tm = tid & 15, tn = tid >> 4;         // 16x16 thread grid
  // acc[r][c]: r 0-3 = rows tm*4+r, r 4-7 = rows 64+tm*4+(r-4)
  float acc[8][4] = {};
  #define PG_FMA(R, AX)                                                   \
    acc[R][0] = fmaf(AX, bb.x, acc[R][0]);                                \
    acc[R][1] = fmaf(AX, bb.y, acc[R][1]);                                \
    acc[R][2] = fmaf(AX, bb.z, acc[R][2]);                                \
    acc[R][3] = fmaf(AX, bb.w, acc[R][3]);
  #pragma unroll 2
  for (int k = 0; k < 100; ++k) {
    float4 a0 = *(const float4*)&As[k][tm * 4];        // banks 4tm: 2-way
    float4 a1 = *(const float4*)&As[k][64 + tm * 4];   // same pattern
    float4 bb = *(const float4*)&Bs[k][tn * 4];        // 4-lane bcast, 2-way
    PG_FMA(0, a0.x) PG_FMA(1, a0.y) PG_FMA(2, a0.z) PG_FMA(3, a0.w)
    PG_FMA(4, a1.x) PG_FMA(5, a1.y) PG_FMA(6, a1.z) PG_FMA(7, a1.w)
  }
  #undef PG_FMA

  if (n0 + tn * 4 < NG) {                         // whole float4 valid or none
    float4 bb = *(const float4*)&bias_s[tn * 4];
    #pragma unroll
    for (int r = 0; r < 8; ++r) {
      int m = m0 + ((r < 4) ? (tm * 4 + r) : (64 + tm * 4 + (r - 4)));
      float4 st;
      st.x = acc[r][0] + bb.x; st.y = acc[r][1] + bb.y;
      st.z = acc[r][2] + bb.z; st.w = acc[r][3] + bb.w;
      *(float4*)&pre[m * NG + n0 + tn * 4] = st;
    }
  }
}

// ---------------------------------------------------------------- kernel 3
// sequential LSTM: 128 blocks (one per e-row), 512 threads. EXACT revert
// to the harness-verified 220us version (R0). R1-R4 post-mortems: fewer
// waves / fewer LDS instrs always lost to AGPR-copy overhead (200 weight
// floats never fit archVGPRs; VGPR=160 + accvgpr moves at 1 wave/SIMD =
// 2625cyc/step vs this structure's 2060). 100 weights/thread in 25 NAMED
// float4 + 7 GEMV waves is the empirical optimum of everything tried.
__device__ __forceinline__ float fast_sigmoid(float x) {
  return 1.f / (1.f + __expf(-x));
}
__device__ __forceinline__ float fast_tanh(float x) {
  float ax = fabsf(x);
  float e  = __expf(-2.f * ax);
  float t  = (1.f - e) / (1.f + e);
  return x < 0.f ? -t : t;
}

#define FMA4(A, W, H)                                                     \
  A = fmaf((H).x, (W).x, A); A = fmaf((H).y, (W).y, A);                   \
  A = fmaf((H).z, (W).z, A); A = fmaf((H).w, (W).w, A)

__global__ __launch_bounds__(512, 2) void k_lstm(
    const float* __restrict__ pre, const float* __restrict__ Whh,
    const int* __restrict__ last, float* __restrict__ truh) {
  __shared__ __align__(16) float h_s[100];
  __shared__ float g_s[NG];
  __shared__ int   last_s[NB];
  const int e = blockIdx.x;         // 0..127
  const int j = threadIdx.x;        // active < 400

  // 25 named float4 = 100 weight VGPRs. Whh row stride 400 B -> 16B aligned.
  float4 w00, w01, w02, w03, w04, w05, w06, w07, w08, w09, w10, w11, w12,
         w13, w14, w15, w16, w17, w18, w19, w20, w21, w22, w23, w24;
  if (j < NG) {
    const float4* wr = (const float4*)(Whh + j * 100);
    w00 = wr[0];  w01 = wr[1];  w02 = wr[2];  w03 = wr[3];  w04 = wr[4];
    w05 = wr[5];  w06 = wr[6];  w07 = wr[7];  w08 = wr[8];  w09 = wr[9];
    w10 = wr[10]; w11 = wr[11]; w12 = wr[12]; w13 = wr[13]; w14 = wr[14];
    w15 = wr[15]; w16 = wr[16]; w17 = wr[17]; w18 = wr[18]; w19 = wr[19];
    w20 = wr[20]; w21 = wr[21]; w22 = wr[22]; w23 = wr[23]; w24 = wr[24];
  }
  if (j < NH) h_s[j] = 0.f;
  if (j < NB) last_s[j] = last[j];  // stage once; avoids per-step global read
  float c = 0.f;                    // cell state for thread j<100

  const float* pbase = pre + e * NG + j;        // + t*51200 per step
  float p0 = (j < NG) ? pbase[0]         : 0.f;
  float p1 = (j < NG) ? pbase[51200]     : 0.f;
  float p2 = (j < NG) ? pbase[2 * 51200] : 0.f;
  __syncthreads();

  for (int t = 0; t < NB; ++t) {
    float p3 = (j < NG && t + 3 < NB) ? pbase[(t + 3) * 51200] : 0.f;

    if (j < NG) {
      // 4 independent accumulator chains; h broadcast from LDS via b128.
      float a0 = p0, a1 = 0.f, a2 = 0.f, a3 = 0.f;
      const float4* h4 = (const float4*)h_s;
      float4 h;
      h = h4[0];  FMA4(a0, w00, h);
      h = h4[1];  FMA4(a1, w01, h);
      h = h4[2];  FMA4(a2, w02, h);
      h = h4[3];  FMA4(a3, w03, h);
      h = h4[4];  FMA4(a0, w04, h);
      h = h4[5];  FMA4(a1, w05, h);
      h = h4[6];  FMA4(a2, w06, h);
      h = h4[7];  FMA4(a3, w07, h);
      h = h4[8];  FMA4(a0, w08, h);
      h = h4[9];  FMA4(a1, w09, h);
      h = h4[10]; FMA4(a2, w10, h);
      h = h4[11]; FMA4(a3, w11, h);
      h = h4[12]; FMA4(a0, w12, h);
      h = h4[13]; FMA4(a1, w13, h);
      h = h4[14]; FMA4(a2, w14, h);
      h = h4[15]; FMA4(a3, w15, h);
      h = h4[16]; FMA4(a0, w16, h);
      h = h4[17]; FMA4(a1, w17, h);
      h = h4[18]; FMA4(a2, w18, h);
      h = h4[19]; FMA4(a3, w19, h);
      h = h4[20]; FMA4(a0, w20, h);
      h = h4[21]; FMA4(a1, w21, h);
      h = h4[22]; FMA4(a2, w22, h);
      h = h4[23]; FMA4(a3, w23, h);
      h = h4[24]; FMA4(a0, w24, h);
      float acc = (a0 + a1) + (a2 + a3);
      float act = (j >= 200 && j < 300) ? fast_tanh(acc) : fast_sigmoid(acc);
      g_s[j] = act;
    }
    __syncthreads();                            // gates visible

    if (j < NH) {
      float ig = g_s[j], fg = g_s[100 + j], gg = g_s[200 + j], og = g_s[300 + j];
      c = fmaf(fg, c, ig * gg);
      float h = og * fast_tanh(c);
      h_s[j] = h;
      if (j == last_s[t]) truh[t * NE + e] = h; // hs[b=t, e, last[t]]
    }
    __syncthreads();                            // h_s(t) visible for step t+1

    p0 = p1; p1 = p2; p2 = p3;
  }
}

// ---------------------------------------------------------------- kernel 4
// out[b] = sigmoid( truh[b,:] . fc_w + fc_b )
__global__ __launch_bounds__(128) void k_fc(
    const float* __restrict__ truh, const float* __restrict__ fcw,
    const float* __restrict__ fcb, float* __restrict__ out) {
  int b = blockIdx.x, t = threadIdx.x;
  float v = truh[b * NE + t] * fcw[t];
  #pragma unroll
  for (int o = 32; o > 0; o >>= 1) v += __shfl_down(v, o);
  __shared__ float s[2];
  if ((t & 63) == 0) s[t >> 6] = v;
  __syncthreads();
  if (t == 0) {
    float sum = s[0] + s[1] + fcb[0];
    out[b] = 1.f / (1.f + __expf(-sum));
  }
}

// ---------------------------------------------------------------- launch
extern "C" void kernel_launch(void* const* d_in, const int* in_sizes, int n_in,
                              void* d_out, int out_size, void* d_ws, size_t ws_size,
                              hipStream_t stream) {
  (void)in_sizes; (void)n_in; (void)out_size; (void)ws_size;
  const int*   diag  = (const int*)d_in[0];
  const float* mask  = (const float*)d_in[1];
  const float* table = (const float*)d_in[2];
  const float* Wih   = (const float*)d_in[3];
  const float* Whh   = (const float*)d_in[4];
  const float* bih   = (const float*)d_in[5];
  const float* bhh   = (const float*)d_in[6];
  const float* fcw   = (const float*)d_in[7];
  const float* fcb   = (const float*)d_in[8];

  float* ws       = (float*)d_ws;
  float* sumembed = ws + OFF_SUM;
  float* pre      = ws + OFF_PRE;
  float* truh     = ws + OFF_TRUH;
  int*   last     = (int*)(ws + OFF_LAST);
  float* out      = (float*)d_out;

  hipMemsetAsync(last, 0, NB * sizeof(int), stream);
  k_embed  <<<dim3(NB * NV), dim3(128), 0, stream>>>(diag, mask, table, sumembed, last);
  k_pregemm<<<dim3(256, 7),  dim3(256), 0, stream>>>(sumembed, Wih, bih, bhh, pre);
  k_lstm   <<<dim3(NE),      dim3(512), 0, stream>>>(pre, Whh, last, truh);
  k_fc     <<<dim3(NB),      dim3(128), 0, stream>>>(truh, fcw, fcb, out);
}